// Round 3
// baseline (2410.734 us; speedup 1.0000x reference)
//
#include <hip/hip_runtime.h>
#include <hip/hip_bf16.h>

#define B_   128
#define L_   512
#define E_   512
#define H_   256
#define K_   64
#define G4H  1024   // 4*H

typedef __bf16 bf16x8 __attribute__((ext_vector_type(8)));
typedef float  f32x4  __attribute__((ext_vector_type(4)));
typedef int    i32x8  __attribute__((ext_vector_type(8)));

__device__ inline unsigned short f2bf(float f) {
    unsigned int x = __builtin_bit_cast(unsigned int, f);
    unsigned int r = (x + 0x7fffu + ((x >> 16) & 1u)) >> 16;
    return (unsigned short)r;
}
__device__ inline float bf2f(unsigned short u) {
    unsigned int x = ((unsigned int)u) << 16;
    return __builtin_bit_cast(float, x);
}
__device__ inline unsigned int pack2(float lo, float hi) {
    return (unsigned int)f2bf(lo) | ((unsigned int)f2bf(hi) << 16);
}

// ---------------------------------------------------------------------------
// Setup: whh -> fp8; w_emit -> bf16; w_ih -> bf16 with gate-interleaved row
// permutation wp[d*1024 + n'] = w_ih_d[(n'&3)*256 + (n'>>2)]; bias_p permuted.
// ---------------------------------------------------------------------------
__global__ void setup_convert(const float* __restrict__ whh_f, const float* __restrict__ whh_b,
                              const float* __restrict__ wemit,
                              const float* __restrict__ wihf, const float* __restrict__ wihb,
                              const float* __restrict__ bihf, const float* __restrict__ bhhf,
                              const float* __restrict__ bihb, const float* __restrict__ bhhb,
                              unsigned char* __restrict__ whh8,
                              unsigned short* __restrict__ wemit_bf,
                              unsigned short* __restrict__ wp,
                              float* __restrict__ bias_p) {
    int i = blockIdx.x * 256 + threadIdx.x;       // grid 1024*256 = 262144
    // whh fp8: 524288 values as 262144 pairs
    if (i < 262144) {
        int j = 2 * i;
        float v0 = (j < 262144) ? whh_f[j] : whh_b[j - 262144];
        float v1 = (j + 1 < 262144) ? whh_f[j + 1] : whh_b[j + 1 - 262144];
        int pk = __builtin_amdgcn_cvt_pk_fp8_f32(v0, v1, 0, false);
        ((unsigned short*)whh8)[i] = (unsigned short)(pk & 0xffff);
    }
    if (i < K_ * 2 * H_) wemit_bf[i] = f2bf(wemit[i]);
    // wp: 2048 rows x 512, 8 elems/thread -> 131072 threads
    if (i < 131072) {
        int rp = i >> 6;            // permuted row 0..2047
        int k8 = (i & 63) * 8;
        int dd = rp >> 10, np = rp & 1023;
        int srow = (np & 3) * 256 + (np >> 2);
        const float* src = (dd == 0 ? wihf : wihb) + (size_t)srow * 512 + k8;
        float4 a  = *reinterpret_cast<const float4*>(src);
        float4 b2 = *reinterpret_cast<const float4*>(src + 4);
        uint4 pk = { pack2(a.x, a.y), pack2(a.z, a.w), pack2(b2.x, b2.y), pack2(b2.z, b2.w) };
        *reinterpret_cast<uint4*>(wp + (size_t)rp * 512 + k8) = pk;
    }
    if (i < 2048) {
        int dd = i >> 10, np = i & 1023;
        int srow = (np & 3) * 256 + (np >> 2);
        bias_p[i] = (dd == 0) ? (bihf[srow] + bhhf[srow]) : (bihb[srow] + bhhb[srow]);
    }
}

// x (B,L,E) fp32 -> bf16, same layout. 33554432 elems, 8/thread.
__global__ void convert_x(const float* __restrict__ x, unsigned short* __restrict__ xb) {
    int i = blockIdx.x * 256 + threadIdx.x;     // 16384 blocks
    float4 a = reinterpret_cast<const float4*>(x)[i * 2];
    float4 b = reinterpret_cast<const float4*>(x)[i * 2 + 1];
    uint4 p = { pack2(a.x, a.y), pack2(a.z, a.w), pack2(b.x, b.y), pack2(b.z, b.w) };
    reinterpret_cast<uint4*>(xb)[i] = p;
}

// ---------------------------------------------------------------------------
// pre3[d][l][b][n'] (bf16), n' = col*4 + gate:  x[b][l][:] . wp[d*1024+n'][:] + bias
// GEMM M = L*B (m = l*128+b), N = 2048, K = 512. 64x64 tiles, bf16 inputs.
// ---------------------------------------------------------------------------
__global__ __launch_bounds__(256) void pre_gemm(
    const unsigned short* __restrict__ xb,    // (B,L,E) bf16
    const unsigned short* __restrict__ wp,    // (2048,512) bf16 permuted
    const float* __restrict__ bias_p,         // (2048) permuted
    unsigned short* __restrict__ pre3)        // [2][512][128][1024]
{
    __shared__ unsigned short lds_a[64][40];
    __shared__ unsigned short lds_b[64][40];

    int nt = blockIdx.x, mt = blockIdx.y;
    int tid = threadIdx.x;
    int n0 = nt * 64, m0 = mt * 64;
    int l = m0 >> 7, b_base = m0 & 127;
    int w = tid >> 6, lane = tid & 63;
    int quad = lane >> 4, ln = lane & 15;
    int wm = (w >> 1) * 32, wn = (w & 1) * 32;

    f32x4 acc[2][2];
    #pragma unroll
    for (int i = 0; i < 2; ++i)
        #pragma unroll
        for (int j = 0; j < 2; ++j) acc[i][j] = (f32x4){0.f, 0.f, 0.f, 0.f};

    int r = tid >> 2, kk = (tid & 3) * 8;
    const unsigned short* arow = xb + (size_t)(b_base + r) * (L_ * E_) + (size_t)l * E_;
    const unsigned short* brow = wp + (size_t)(n0 + r) * E_;

    for (int kc = 0; kc < 16; ++kc) {
        int k0 = kc * 32;
        uint4 va = *reinterpret_cast<const uint4*>(arow + k0 + kk);
        uint4 vb = *reinterpret_cast<const uint4*>(brow + k0 + kk);
        __syncthreads();
        *reinterpret_cast<uint4*>(&lds_a[r][kk]) = va;
        *reinterpret_cast<uint4*>(&lds_b[r][kk]) = vb;
        __syncthreads();

        bf16x8 af[2], bfv[2];
        #pragma unroll
        for (int ms = 0; ms < 2; ++ms)
            af[ms] = *reinterpret_cast<const bf16x8*>(&lds_a[wm + ms * 16 + ln][quad * 8]);
        #pragma unroll
        for (int ns = 0; ns < 2; ++ns)
            bfv[ns] = *reinterpret_cast<const bf16x8*>(&lds_b[wn + ns * 16 + ln][quad * 8]);
        #pragma unroll
        for (int ms = 0; ms < 2; ++ms)
            #pragma unroll
            for (int ns = 0; ns < 2; ++ns)
                acc[ms][ns] = __builtin_amdgcn_mfma_f32_16x16x32_bf16(af[ms], bfv[ns], acc[ms][ns], 0, 0, 0);
    }

    #pragma unroll
    for (int ns = 0; ns < 2; ++ns) {
        int n = n0 + wn + ns * 16 + ln;
        float bias = bias_p[n];
        int dsel = n >> 10, np = n & 1023;
        #pragma unroll
        for (int ms = 0; ms < 2; ++ms) {
            #pragma unroll
            for (int rg = 0; rg < 4; ++rg) {
                int m = m0 + wm + ms * 16 + quad * 4 + rg;
                int b = m & 127;
                pre3[(((size_t)dsel * L_ + l) * B_ + b) * 1024 + np] = f2bf(acc[ms][ns][rg] + bias);
            }
        }
    }
}

// ---------------------------------------------------------------------------
// LSTM scan: 16 WGs (d = wg>>3, 16 batch rows), 512 threads = 8 waves.
// MX fp8 MFMA 16x16x128 (identity scales). W_hh register-resident (128 VGPR).
// Wave w owns tiles T = g*16 + (w+8s): all 4 gates for hidden cols
// (w+8s)*16+ln live in one lane's acc -> in-register activation, one barrier.
// pre read directly from HBM per-lane (b64 = 4 gates), prefetched 1 step.
// ---------------------------------------------------------------------------
__global__ __launch_bounds__(512, 2) void lstm_scan(
    const unsigned short* __restrict__ pre3,  // [2][512][128][1024] bf16
    const unsigned char* __restrict__ whh8,   // [2][1024][256] fp8 e4m3
    unsigned short* __restrict__ hcat)        // [512][128][512] bf16
{
    __shared__ unsigned char h_lds[2][16 * 272];   // pitch 272 = 16*17 (odd x16 -> spread banks)

    int wg = blockIdx.x;
    int d = wg >> 3, bs = wg & 7, b0 = bs * 16;
    int tid = threadIdx.x, w = tid >> 6, lane = tid & 63;
    int q = lane >> 4, ln = lane & 15;

    const unsigned char* whh_d = whh8 + (size_t)d * (1024 * 256);
    const unsigned short* pre_d = pre3 + (size_t)d * (512 * 128 * 1024);

    // B-frags: B[n=ln][k = kc*128 + q*32 + j], W row = g*256 + (w+8s)*16 + ln
    i32x8 wh[4][2][2];
    #pragma unroll
    for (int g = 0; g < 4; ++g)
        #pragma unroll
        for (int s = 0; s < 2; ++s) {
            int row = g * 256 + (w + 8 * s) * 16 + ln;
            #pragma unroll
            for (int kc = 0; kc < 2; ++kc)
                wh[g][s][kc] = *reinterpret_cast<const i32x8*>(
                    whh_d + (size_t)row * 256 + kc * 128 + q * 32);
        }

    for (int i = tid; i < (2 * 16 * 272) / 4; i += 512) ((int*)h_lds)[i] = 0;

    int myrow = q * 4;                 // batch-local rows myrow..myrow+3
    int colb[2];
    colb[0] = w * 16 + ln;
    colb[1] = (w + 8) * 16 + ln;

    ushort4 pcur[2][4], pnext[2][4];
    {
        int l0 = (d == 0) ? 0 : (L_ - 1);
        const unsigned short* pl = pre_d + ((size_t)l0 * B_ + b0) * 1024;
        #pragma unroll
        for (int s = 0; s < 2; ++s)
            #pragma unroll
            for (int r = 0; r < 4; ++r)
                pcur[s][r] = *reinterpret_cast<const ushort4*>(
                    pl + (size_t)(myrow + r) * 1024 + colb[s] * 4);
    }
    __syncthreads();

    float cst[2][4] = {{0.f,0.f,0.f,0.f},{0.f,0.f,0.f,0.f}};

    for (int t = 0; t < L_; ++t) {
        int p = t & 1;
        int l = (d == 0) ? t : (L_ - 1 - t);
        int tn = (t + 1 < L_) ? (t + 1) : t;
        int lnext = (d == 0) ? tn : (L_ - 1 - tn);

        // prefetch pre[t+1] into regs (latency hidden behind MFMA + act)
        {
            const unsigned short* pl = pre_d + ((size_t)lnext * B_ + b0) * 1024;
            #pragma unroll
            for (int s = 0; s < 2; ++s)
                #pragma unroll
                for (int r = 0; r < 4; ++r)
                    pnext[s][r] = *reinterpret_cast<const ushort4*>(
                        pl + (size_t)(myrow + r) * 1024 + colb[s] * 4);
        }

        // ---- MFMA: G = h @ W_hh^T  (MX fp8, K=256 in 2 chunks of 128) ----
        f32x4 acc[4][2];
        #pragma unroll
        for (int g = 0; g < 4; ++g) {
            acc[g][0] = (f32x4){0.f, 0.f, 0.f, 0.f};
            acc[g][1] = (f32x4){0.f, 0.f, 0.f, 0.f};
        }
        #pragma unroll
        for (int kc = 0; kc < 2; ++kc) {
            const unsigned char* ab = &h_lds[p][ln * 272 + kc * 128 + q * 32];
            uint4 a0 = *reinterpret_cast<const uint4*>(ab);
            uint4 a1 = *reinterpret_cast<const uint4*>(ab + 16);
            i32x8 af = { (int)a0.x, (int)a0.y, (int)a0.z, (int)a0.w,
                         (int)a1.x, (int)a1.y, (int)a1.z, (int)a1.w };
            #pragma unroll
            for (int g = 0; g < 4; ++g)
                #pragma unroll
                for (int s = 0; s < 2; ++s)
                    acc[g][s] = __builtin_amdgcn_mfma_scale_f32_16x16x128_f8f6f4(
                        af, wh[g][s][kc], acc[g][s], 0, 0,
                        0, 0x7f7f7f7f, 0, 0x7f7f7f7f);
        }

        // ---- in-register activation: rows myrow..+3, cols colb[s] ----
        #pragma unroll
        for (int s = 0; s < 2; ++s) {
            float hn[4];
            #pragma unroll
            for (int r = 0; r < 4; ++r) {
                float vi = acc[0][s][r] + bf2f(pcur[s][r].x);
                float vf = acc[1][s][r] + bf2f(pcur[s][r].y);
                float vg = acc[2][s][r] + bf2f(pcur[s][r].z);
                float vo = acc[3][s][r] + bf2f(pcur[s][r].w);
                float ei  = __expf(vi);
                float ef  = __expf(vf);
                float e2g = __expf(2.f * vg);
                float fs  = ef * __builtin_amdgcn_rcpf(1.f + ef);
                float itg = (ei * (e2g - 1.f)) * __builtin_amdgcn_rcpf((1.f + ei) * (1.f + e2g));
                float cn  = fs * cst[s][r] + itg;
                cst[s][r] = cn;
                float eo  = __expf(vo);
                float e2c = __expf(2.f * cn);
                hn[r] = (eo * (e2c - 1.f)) * __builtin_amdgcn_rcpf((1.f + eo) * (1.f + e2c));
            }
            int pk01 = __builtin_amdgcn_cvt_pk_fp8_f32(hn[0], hn[1], 0, false);
            int pk23 = __builtin_amdgcn_cvt_pk_fp8_f32(hn[2], hn[3], 0, false);
            unsigned char* hb = &h_lds[p ^ 1][colb[s]];
            hb[(myrow + 0) * 272] = (unsigned char)(pk01 & 0xff);
            hb[(myrow + 1) * 272] = (unsigned char)((pk01 >> 8) & 0xff);
            hb[(myrow + 2) * 272] = (unsigned char)(pk23 & 0xff);
            hb[(myrow + 3) * 272] = (unsigned char)((pk23 >> 8) & 0xff);
            unsigned short* hc = hcat + ((size_t)l * B_ + b0 + myrow) * (2 * H_) + d * H_ + colb[s];
            hc[0]        = f2bf(hn[0]);
            hc[512]      = f2bf(hn[1]);
            hc[1024]     = f2bf(hn[2]);
            hc[1536]     = f2bf(hn[3]);
        }
        __syncthreads();
        #pragma unroll
        for (int s = 0; s < 2; ++s)
            #pragma unroll
            for (int r = 0; r < 4; ++r) pcur[s][r] = pnext[s][r];
    }
}

// ---------------------------------------------------------------------------
// emit[b][l][k] = hcat[l][b][:] . w_emit[k][:] + b_emit[k]   (fp32 out)
// ---------------------------------------------------------------------------
__global__ __launch_bounds__(256) void emit_gemm(
    const unsigned short* __restrict__ hcat,   // [L*B][512]
    const unsigned short* __restrict__ wemit,  // [64][512]
    const float* __restrict__ bemit,           // [64]
    float* __restrict__ emit)                  // [B][L][64]
{
    int m0 = blockIdx.x * 64;
    int tid = threadIdx.x, w = tid >> 6, lane = tid & 63;
    int quad = lane >> 4, ln = lane & 15;
    int mrow = m0 + w * 16;

    f32x4 acc[4];
    #pragma unroll
    for (int i = 0; i < 4; ++i) acc[i] = (f32x4){0.f, 0.f, 0.f, 0.f};

    const unsigned short* arow = hcat + (size_t)(mrow + ln) * 512;
    #pragma unroll 4
    for (int kc = 0; kc < 16; ++kc) {
        bf16x8 af = *reinterpret_cast<const bf16x8*>(arow + kc * 32 + quad * 8);
        #pragma unroll
        for (int T = 0; T < 4; ++T) {
            bf16x8 bfv = *reinterpret_cast<const bf16x8*>(wemit + (size_t)(T * 16 + ln) * 512 + kc * 32 + quad * 8);
            acc[T] = __builtin_amdgcn_mfma_f32_16x16x32_bf16(af, bfv, acc[T], 0, 0, 0);
        }
    }
    #pragma unroll
    for (int T = 0; T < 4; ++T) {
        int k = T * 16 + ln;
        float bias = bemit[k];
        #pragma unroll
        for (int rg = 0; rg < 4; ++rg) {
            int m = mrow + quad * 4 + rg;
            int ll = m >> 7, bidx = m & 127;
            emit[((size_t)bidx * L_ + ll) * K_ + k] = acc[T][rg] + bias;
        }
    }
}

// ---------------------------------------------------------------------------
// CRF: per batch row, 511 sequential steps.
// lse_i(d_i + T[i,k]) = M + log( sum_i exp(d_i - M) * expT[i][k] ),  M = max_i d_i
// ---------------------------------------------------------------------------
__global__ __launch_bounds__(64) void crf_kernel(
    const float* __restrict__ emit,    // [B][L][64]
    const int* __restrict__ labels,    // [B][L]
    const float* __restrict__ trans,   // [64][64]
    float* __restrict__ out)           // [B]
{
    __shared__ float els[64];
    int b = blockIdx.x, lane = threadIdx.x;
    const float* eb = emit + (size_t)b * L_ * K_;
    const int* lb = labels + (size_t)b * L_;

    float gold = 0.f;
    for (int t = lane; t < L_; t += 64) gold += eb[(size_t)t * K_ + lb[t]];
    for (int t = lane; t < L_ - 1; t += 64) gold += trans[lb[t] * K_ + lb[t + 1]];
    #pragma unroll
    for (int off = 32; off; off >>= 1) gold += __shfl_down(gold, off);

    float expT[64];   // column `lane` of exp(T)
    #pragma unroll
    for (int i = 0; i < 64; ++i) expT[i] = __expf(trans[i * K_ + lane]);

    float dstate = eb[lane];
    float enext = eb[K_ + lane];
    for (int t = 1; t < L_; ++t) {
        float ecur = enext;
        if (t + 1 < L_) enext = eb[(size_t)(t + 1) * K_ + lane];
        float M = dstate;
        #pragma unroll
        for (int off = 32; off; off >>= 1) M = fmaxf(M, __shfl_xor(M, off));
        float e = __expf(dstate - M);
        __syncthreads();
        els[lane] = e;
        __syncthreads();
        float s = 0.f;
        #pragma unroll
        for (int i = 0; i < 64; i += 4) {
            float4 ev = *reinterpret_cast<const float4*>(&els[i]);
            s = fmaf(ev.x, expT[i], s);
            s = fmaf(ev.y, expT[i + 1], s);
            s = fmaf(ev.z, expT[i + 2], s);
            s = fmaf(ev.w, expT[i + 3], s);
        }
        dstate = M + __logf(s) + ecur;
    }
    float M = dstate;
    #pragma unroll
    for (int off = 32; off; off >>= 1) M = fmaxf(M, __shfl_xor(M, off));
    float e = __expf(dstate - M);
    float s = e;
    #pragma unroll
    for (int off = 32; off; off >>= 1) s += __shfl_xor(s, off);
    float logZ = M + __logf(s);
    if (lane == 0) out[b] = -(gold - logZ);
}

// ---------------------------------------------------------------------------
// Workspace layout (bytes). Overlays (disjoint lifetimes):
//   xb aliases hcat  (xb dead after pre_gemm; hcat written in lstm_scan)
//   emit aliases pre3 head (pre3 dead after lstm_scan)
// ---------------------------------------------------------------------------
#define OFF_PRE    ((size_t)0)                        // 2*512*128*1024*2 = 268435456
#define OFF_EMIT   OFF_PRE                            // 128*512*64*4 = 16777216 (alias)
#define OFF_HCAT   ((size_t)268435456)                // 512*128*512*2 = 67108864
#define OFF_XB     OFF_HCAT                           // 33554432*2 = 67108864 (alias)
#define OFF_WHH8   ((size_t)(OFF_HCAT + 67108864))    // 524288
#define OFF_WEMIT  ((size_t)(OFF_WHH8 + 524288))      // 65536
#define OFF_WP     ((size_t)(OFF_WEMIT + 65536))      // 2048*512*2 = 2097152
#define OFF_BIAS   ((size_t)(OFF_WP + 2097152))       // 8192

extern "C" void kernel_launch(void* const* d_in, const int* in_sizes, int n_in,
                              void* d_out, int out_size, void* d_ws, size_t ws_size,
                              hipStream_t stream) {
    const float* x      = (const float*)d_in[0];
    const int*   labels = (const int*)d_in[1];
    const float* wihf   = (const float*)d_in[2];
    const float* whhf   = (const float*)d_in[3];
    const float* bihf   = (const float*)d_in[4];
    const float* bhhf   = (const float*)d_in[5];
    const float* wihb   = (const float*)d_in[6];
    const float* whhb   = (const float*)d_in[7];
    const float* bihb   = (const float*)d_in[8];
    const float* bhhb   = (const float*)d_in[9];
    const float* wemit  = (const float*)d_in[10];
    const float* bemit  = (const float*)d_in[11];
    const float* trans  = (const float*)d_in[12];
    float* out = (float*)d_out;

    char* ws = (char*)d_ws;
    unsigned short* pre3   = (unsigned short*)(ws + OFF_PRE);
    unsigned short* hcat   = (unsigned short*)(ws + OFF_HCAT);
    unsigned short* xb     = (unsigned short*)(ws + OFF_XB);
    float*          emit   = (float*)(ws + OFF_EMIT);
    unsigned char*  whh8   = (unsigned char*)(ws + OFF_WHH8);
    unsigned short* we_bf  = (unsigned short*)(ws + OFF_WEMIT);
    unsigned short* wp     = (unsigned short*)(ws + OFF_WP);
    float*          bias_p = (float*)(ws + OFF_BIAS);

    setup_convert<<<1024, 256, 0, stream>>>(whhf, whhb, wemit, wihf, wihb,
                                            bihf, bhhf, bihb, bhhb,
                                            whh8, we_bf, wp, bias_p);
    convert_x<<<16384, 256, 0, stream>>>(x, xb);
    pre_gemm<<<dim3(32, 1024), 256, 0, stream>>>(xb, wp, bias_p, pre3);
    lstm_scan<<<16, 512, 0, stream>>>(pre3, whh8, hcat);
    emit_gemm<<<1024, 256, 0, stream>>>(hcat, we_bf, bemit, emit);
    crf_kernel<<<128, 64, 0, stream>>>(emit, labels, trans, out);
}

// Round 4
// 1630.326 us; speedup vs baseline: 1.4787x; 1.4787x over previous
//
#include <hip/hip_runtime.h>
#include <hip/hip_bf16.h>

#define B_   128
#define L_   512
#define E_   512
#define H_   256
#define K_   64
#define G4H  1024   // 4*H
#define LOG2E 1.4426950408889634f

typedef __bf16 bf16x8 __attribute__((ext_vector_type(8)));
typedef float  f32x4  __attribute__((ext_vector_type(4)));
typedef int    i32x8  __attribute__((ext_vector_type(8)));

__device__ inline unsigned short f2bf(float f) {
    unsigned int x = __builtin_bit_cast(unsigned int, f);
    unsigned int r = (x + 0x7fffu + ((x >> 16) & 1u)) >> 16;
    return (unsigned short)r;
}
__device__ inline float bf2f(unsigned short u) {
    unsigned int x = ((unsigned int)u) << 16;
    return __builtin_bit_cast(float, x);
}
__device__ inline unsigned int pack2(float lo, float hi) {
    return (unsigned int)f2bf(lo) | ((unsigned int)f2bf(hi) << 16);
}
__device__ inline float ex2(float x) { return __builtin_amdgcn_exp2f(x); }

// async global->LDS, 16B per lane; LDS dest must be wave-uniform + lane*16
__device__ inline void gl_lds16(const unsigned short* g, unsigned short* l) {
    __builtin_amdgcn_global_load_lds(
        (const __attribute__((address_space(1))) unsigned int*)g,
        (__attribute__((address_space(3))) unsigned int*)l, 16, 0, 0);
}

// ---------------------------------------------------------------------------
// Setup: whh -> fp8 e4m3 scaled by LOG2E; w_emit -> bf16;
// w_ih -> bf16 * LOG2E with gate-interleaved row perm wp[n'=col*4+gate];
// bias_p = (b_ih + b_hh) * LOG2E, permuted.
// ---------------------------------------------------------------------------
__global__ void setup_convert(const float* __restrict__ whh_f, const float* __restrict__ whh_b,
                              const float* __restrict__ wemit,
                              const float* __restrict__ wihf, const float* __restrict__ wihb,
                              const float* __restrict__ bihf, const float* __restrict__ bhhf,
                              const float* __restrict__ bihb, const float* __restrict__ bhhb,
                              unsigned char* __restrict__ whh8,
                              unsigned short* __restrict__ wemit_bf,
                              unsigned short* __restrict__ wp,
                              float* __restrict__ bias_p) {
    int i = blockIdx.x * 256 + threadIdx.x;       // grid 1024*256 = 262144
    if (i < 262144) {
        int j = 2 * i;
        float v0 = (j < 262144) ? whh_f[j] : whh_b[j - 262144];
        float v1 = (j + 1 < 262144) ? whh_f[j + 1] : whh_b[j + 1 - 262144];
        int pk = __builtin_amdgcn_cvt_pk_fp8_f32(v0 * LOG2E, v1 * LOG2E, 0, false);
        ((unsigned short*)whh8)[i] = (unsigned short)(pk & 0xffff);
    }
    if (i < K_ * 2 * H_) wemit_bf[i] = f2bf(wemit[i]);
    if (i < 131072) {
        int rp = i >> 6;            // permuted row 0..2047
        int k8 = (i & 63) * 8;
        int dd = rp >> 10, np = rp & 1023;
        int srow = (np & 3) * 256 + (np >> 2);
        const float* src = (dd == 0 ? wihf : wihb) + (size_t)srow * 512 + k8;
        float4 a  = *reinterpret_cast<const float4*>(src);
        float4 b2 = *reinterpret_cast<const float4*>(src + 4);
        uint4 pk = { pack2(a.x * LOG2E, a.y * LOG2E), pack2(a.z * LOG2E, a.w * LOG2E),
                     pack2(b2.x * LOG2E, b2.y * LOG2E), pack2(b2.z * LOG2E, b2.w * LOG2E) };
        *reinterpret_cast<uint4*>(wp + (size_t)rp * 512 + k8) = pk;
    }
    if (i < 2048) {
        int dd = i >> 10, np = i & 1023;
        int srow = (np & 3) * 256 + (np >> 2);
        bias_p[i] = ((dd == 0) ? (bihf[srow] + bhhf[srow]) : (bihb[srow] + bhhb[srow])) * LOG2E;
    }
}

// x (B,L,E) fp32 -> bf16, same layout
__global__ void convert_x(const float* __restrict__ x, unsigned short* __restrict__ xb) {
    int i = blockIdx.x * 256 + threadIdx.x;     // 16384 blocks
    float4 a = reinterpret_cast<const float4*>(x)[i * 2];
    float4 b = reinterpret_cast<const float4*>(x)[i * 2 + 1];
    uint4 p = { pack2(a.x, a.y), pack2(a.z, a.w), pack2(b.x, b.y), pack2(b.z, b.w) };
    reinterpret_cast<uint4*>(xb)[i] = p;
}

// ---------------------------------------------------------------------------
// pre3[d][l][b][n'] (bf16), n' = col*4+gate, scaled by LOG2E.
// m97-style: 128x128 tile, BK=32, global_load_lds(16B). M-tile = one b, 128 l.
// ---------------------------------------------------------------------------
__global__ __launch_bounds__(256) void pre_gemm(
    const unsigned short* __restrict__ xb,    // (B,L,E) bf16
    const unsigned short* __restrict__ wp,    // (2048,512) bf16 permuted*LOG2E
    const float* __restrict__ bias_p,         // (2048) permuted*LOG2E
    unsigned short* __restrict__ pre3)        // [2][512][128][1024]
{
    __shared__ unsigned short A_lds[128 * 32];   // [row][k], 64B/row (no pad: DMA linear)
    __shared__ unsigned short B_lds[128 * 32];

    int nt = blockIdx.x, mt = blockIdx.y;
    int tid = threadIdx.x;
    int n0 = nt * 128;
    int b  = mt >> 2, l0 = (mt & 3) * 128;
    int w = tid >> 6, lane = tid & 63;
    int q = lane >> 4, ln = lane & 15;
    int wm = (w >> 1) * 64, wn = (w & 1) * 64;

    f32x4 acc[4][4];
    #pragma unroll
    for (int i = 0; i < 4; ++i)
        #pragma unroll
        for (int j = 0; j < 4; ++j) acc[i][j] = (f32x4){0.f, 0.f, 0.f, 0.f};

    int r_ = tid >> 2, kp = (tid & 3) * 8;
    const unsigned short* asrc0 = xb + ((size_t)b * 512 + l0 + r_) * 512 + kp;
    const unsigned short* asrc1 = asrc0 + (size_t)64 * 512;
    const unsigned short* bsrc0 = wp + (size_t)(n0 + r_) * 512 + kp;
    const unsigned short* bsrc1 = bsrc0 + (size_t)64 * 512;
    unsigned short* adst0 = &A_lds[tid * 8];
    unsigned short* adst1 = &A_lds[2048 + tid * 8];
    unsigned short* bdst0 = &B_lds[tid * 8];
    unsigned short* bdst1 = &B_lds[2048 + tid * 8];

    for (int kc = 0; kc < 16; ++kc) {
        int k0 = kc * 32;
        gl_lds16(asrc0 + k0, adst0);
        gl_lds16(asrc1 + k0, adst1);
        gl_lds16(bsrc0 + k0, bdst0);
        gl_lds16(bsrc1 + k0, bdst1);
        __syncthreads();   // drains vmcnt -> LDS filled

        bf16x8 af[4], bfv[4];
        #pragma unroll
        for (int ms = 0; ms < 4; ++ms)
            af[ms] = *reinterpret_cast<const bf16x8*>(&A_lds[(wm + ms * 16 + ln) * 32 + q * 8]);
        #pragma unroll
        for (int ns = 0; ns < 4; ++ns)
            bfv[ns] = *reinterpret_cast<const bf16x8*>(&B_lds[(wn + ns * 16 + ln) * 32 + q * 8]);
        #pragma unroll
        for (int ms = 0; ms < 4; ++ms)
            #pragma unroll
            for (int ns = 0; ns < 4; ++ns)
                acc[ms][ns] = __builtin_amdgcn_mfma_f32_16x16x32_bf16(af[ms], bfv[ns], acc[ms][ns], 0, 0, 0);
        __syncthreads();   // frag reads done before next DMA overwrites
    }

    #pragma unroll
    for (int ns = 0; ns < 4; ++ns) {
        int n = n0 + wn + ns * 16 + ln;
        float bias = bias_p[n];
        int dsel = n >> 10, np = n & 1023;
        #pragma unroll
        for (int ms = 0; ms < 4; ++ms) {
            #pragma unroll
            for (int rg = 0; rg < 4; ++rg) {
                int l = l0 + wm + ms * 16 + q * 4 + rg;
                pre3[(((size_t)dsel * 512 + l) * 128 + b) * 1024 + np] = f2bf(acc[ms][ns][rg] + bias);
            }
        }
    }
}

// ---------------------------------------------------------------------------
// LSTM scan: 32 WGs (d = wg>>4, 8 batch rows), 512 threads = 8 waves.
// MX fp8 MFMA 16x16x128, W_hh register-resident (128 VGPR), inputs pre-scaled
// by LOG2E so activations use raw v_exp_f32 (exp2).
// Per step: MFMA -> g_lds[row][n'] f32 -> balanced activation (4 units/thread,
// gates read as one b128) -> h to fp8 h_lds + coalesced bf16 hcat.
// ---------------------------------------------------------------------------
#define GP 1036   // g_lds row pitch in floats (stride%32=12 -> write sets split; reads contiguous)
__global__ __launch_bounds__(512, 2) void lstm_scan(
    const unsigned short* __restrict__ pre3,  // [2][512][128][1024] bf16 (scaled)
    const unsigned char* __restrict__ whh8,   // [2][1024][256] fp8 e4m3 (scaled)
    unsigned short* __restrict__ hcat)        // [512][128][512] bf16
{
    __shared__ unsigned char h_lds[2][16 * 272];   // fp8; rows 8..15 stay 0
    __shared__ float g_lds[8 * GP];                // [row][n'=col*4+gate]

    int wg = blockIdx.x;
    int d = wg >> 4, bs = wg & 15, b0 = bs * 8;
    int tid = threadIdx.x, w = tid >> 6, lane = tid & 63;
    int q = lane >> 4, ln = lane & 15;

    const unsigned char* whh_d = whh8 + (size_t)d * (1024 * 256);
    const unsigned short* pre_d = pre3 + (size_t)d * (512 * 128 * 1024);

    // W_hh B-frags: tile T = g*16 + (w+8s); B[n=T*16+ln][k=kc*128+q*32+j]
    i32x8 wh[4][2][2];
    #pragma unroll
    for (int g = 0; g < 4; ++g)
        #pragma unroll
        for (int s = 0; s < 2; ++s) {
            int row = g * 256 + (w + 8 * s) * 16 + ln;
            #pragma unroll
            for (int kc = 0; kc < 2; ++kc)
                wh[g][s][kc] = *reinterpret_cast<const i32x8*>(
                    whh_d + (size_t)row * 256 + kc * 128 + q * 32);
        }

    for (int i = tid; i < (2 * 16 * 272) / 4; i += 512) ((int*)h_lds)[i] = 0;

    // activation assignment: thread -> col = tid&255, rows rg4..rg4+3
    int col  = tid & 255;
    int rg4  = (tid >> 8) * 4;
    int coff = col * 4;                 // n' base

    ushort4 pcur[4], pnext[4];
    {
        int l0 = (d == 0) ? 0 : (L_ - 1);
        #pragma unroll
        for (int k2 = 0; k2 < 4; ++k2)
            pcur[k2] = *reinterpret_cast<const ushort4*>(
                pre_d + ((size_t)l0 * 128 + b0 + rg4 + k2) * 1024 + coff);
    }
    __syncthreads();

    float cst[4] = {0.f, 0.f, 0.f, 0.f};

    for (int t = 0; t < L_; ++t) {
        int p = t & 1;
        int l = (d == 0) ? t : (L_ - 1 - t);
        int tn = (t + 1 < L_) ? (t + 1) : t;
        int lnext = (d == 0) ? tn : (L_ - 1 - tn);

        // prefetch pre[t+1] (latency hidden across the whole step)
        #pragma unroll
        for (int k2 = 0; k2 < 4; ++k2)
            pnext[k2] = *reinterpret_cast<const ushort4*>(
                pre_d + ((size_t)lnext * 128 + b0 + rg4 + k2) * 1024 + coff);

        // ---- MFMA: G = h @ W_hh^T (MX fp8, K=256 = 2 chunks of 128) ----
        f32x4 acc[4][2];
        #pragma unroll
        for (int g = 0; g < 4; ++g) {
            acc[g][0] = (f32x4){0.f, 0.f, 0.f, 0.f};
            acc[g][1] = (f32x4){0.f, 0.f, 0.f, 0.f};
        }
        #pragma unroll
        for (int kc = 0; kc < 2; ++kc) {
            const unsigned char* ab = &h_lds[p][ln * 272 + kc * 128 + q * 32];
            uint4 a0 = *reinterpret_cast<const uint4*>(ab);
            uint4 a1 = *reinterpret_cast<const uint4*>(ab + 16);
            i32x8 af = { (int)a0.x, (int)a0.y, (int)a0.z, (int)a0.w,
                         (int)a1.x, (int)a1.y, (int)a1.z, (int)a1.w };
            #pragma unroll
            for (int g = 0; g < 4; ++g)
                #pragma unroll
                for (int s = 0; s < 2; ++s)
                    acc[g][s] = __builtin_amdgcn_mfma_scale_f32_16x16x128_f8f6f4(
                        af, wh[g][s][kc], acc[g][s], 0, 0,
                        0, 0x7f7f7f7f, 0, 0x7f7f7f7f);
        }

        // ---- scatter valid rows (q<2 -> batch rows q*4+r) to g_lds ----
        if (q < 2) {
            #pragma unroll
            for (int g = 0; g < 4; ++g)
                #pragma unroll
                for (int s = 0; s < 2; ++s) {
                    int cp = ((w + 8 * s) * 16 + ln) * 4 + g;
                    #pragma unroll
                    for (int r = 0; r < 4; ++r)
                        g_lds[(q * 4 + r) * GP + cp] = acc[g][s][r];
                }
        }
        __syncthreads();

        // ---- balanced activation: 4 units (rows rg4..+3, col) ----
        float hn[4];
        #pragma unroll
        for (int k2 = 0; k2 < 4; ++k2) {
            f32x4 gv = *reinterpret_cast<const f32x4*>(&g_lds[(rg4 + k2) * GP + coff]);
            float vi = gv.x + bf2f(pcur[k2].x);
            float vf = gv.y + bf2f(pcur[k2].y);
            float vg = gv.z + bf2f(pcur[k2].z);
            float vo = gv.w + bf2f(pcur[k2].w);
            float si = __builtin_amdgcn_rcpf(1.f + ex2(-vi));
            float sf = __builtin_amdgcn_rcpf(1.f + ex2(-vf));
            float tg = fmaf(2.f, __builtin_amdgcn_rcpf(1.f + ex2(-(vg + vg))), -1.f);
            float so = __builtin_amdgcn_rcpf(1.f + ex2(-vo));
            float cn = fmaf(sf, cst[k2], si * tg);
            cst[k2] = cn;
            float tc = fmaf(2.f, __builtin_amdgcn_rcpf(1.f + ex2(cn * (-2.f * LOG2E))), -1.f);
            hn[k2] = so * tc;
        }
        // h -> fp8 h_lds (next MFMA input) + coalesced bf16 hcat
        int pk01 = __builtin_amdgcn_cvt_pk_fp8_f32(hn[0], hn[1], 0, false);
        int pk23 = __builtin_amdgcn_cvt_pk_fp8_f32(hn[2], hn[3], 0, false);
        unsigned char* hb = &h_lds[p ^ 1][col];
        hb[(rg4 + 0) * 272] = (unsigned char)(pk01 & 0xff);
        hb[(rg4 + 1) * 272] = (unsigned char)((pk01 >> 8) & 0xff);
        hb[(rg4 + 2) * 272] = (unsigned char)(pk23 & 0xff);
        hb[(rg4 + 3) * 272] = (unsigned char)((pk23 >> 8) & 0xff);
        unsigned short* hc = hcat + ((size_t)l * 128 + b0 + rg4) * 512 + d * 256 + col;
        hc[0]    = f2bf(hn[0]);
        hc[512]  = f2bf(hn[1]);
        hc[1024] = f2bf(hn[2]);
        hc[1536] = f2bf(hn[3]);
        __syncthreads();   // h_lds[p^1] ready; g_lds reads done before next scatter

        #pragma unroll
        for (int k2 = 0; k2 < 4; ++k2) pcur[k2] = pnext[k2];
    }
}

// ---------------------------------------------------------------------------
// emit[b][l][k] = hcat[l][b][:] . w_emit[k][:] + b_emit[k]   (fp32 out)
// ---------------------------------------------------------------------------
__global__ __launch_bounds__(256) void emit_gemm(
    const unsigned short* __restrict__ hcat,   // [L*B][512]
    const unsigned short* __restrict__ wemit,  // [64][512]
    const float* __restrict__ bemit,           // [64]
    float* __restrict__ emit)                  // [B][L][64]
{
    int m0 = blockIdx.x * 64;
    int tid = threadIdx.x, w = tid >> 6, lane = tid & 63;
    int quad = lane >> 4, ln = lane & 15;
    int mrow = m0 + w * 16;

    f32x4 acc[4];
    #pragma unroll
    for (int i = 0; i < 4; ++i) acc[i] = (f32x4){0.f, 0.f, 0.f, 0.f};

    const unsigned short* arow = hcat + (size_t)(mrow + ln) * 512;
    #pragma unroll 4
    for (int kc = 0; kc < 16; ++kc) {
        bf16x8 af = *reinterpret_cast<const bf16x8*>(arow + kc * 32 + quad * 8);
        #pragma unroll
        for (int T = 0; T < 4; ++T) {
            bf16x8 bfv = *reinterpret_cast<const bf16x8*>(wemit + (size_t)(T * 16 + ln) * 512 + kc * 32 + quad * 8);
            acc[T] = __builtin_amdgcn_mfma_f32_16x16x32_bf16(af, bfv, acc[T], 0, 0, 0);
        }
    }
    #pragma unroll
    for (int T = 0; T < 4; ++T) {
        int k = T * 16 + ln;
        float bias = bemit[k];
        #pragma unroll
        for (int rg = 0; rg < 4; ++rg) {
            int m = mrow + quad * 4 + rg;
            int ll = m >> 7, bidx = m & 127;
            emit[((size_t)bidx * L_ + ll) * K_ + k] = acc[T][rg] + bias;
        }
    }
}

// ---------------------------------------------------------------------------
// CRF: per batch row, 511 sequential steps.
// lse_i(d_i + T[i,k]) = M + log( sum_i exp(d_i - M) * expT[i][k] )
// ---------------------------------------------------------------------------
__global__ __launch_bounds__(64) void crf_kernel(
    const float* __restrict__ emit,    // [B][L][64]
    const int* __restrict__ labels,    // [B][L]
    const float* __restrict__ trans,   // [64][64]
    float* __restrict__ out)           // [B]
{
    __shared__ float els[64];
    int b = blockIdx.x, lane = threadIdx.x;
    const float* eb = emit + (size_t)b * L_ * K_;
    const int* lb = labels + (size_t)b * L_;

    float gold = 0.f;
    for (int t = lane; t < L_; t += 64) gold += eb[(size_t)t * K_ + lb[t]];
    for (int t = lane; t < L_ - 1; t += 64) gold += trans[lb[t] * K_ + lb[t + 1]];
    #pragma unroll
    for (int off = 32; off; off >>= 1) gold += __shfl_down(gold, off);

    float expT[64];   // column `lane` of exp(T)
    #pragma unroll
    for (int i = 0; i < 64; ++i) expT[i] = __expf(trans[i * K_ + lane]);

    float dstate = eb[lane];
    float enext = eb[K_ + lane];
    for (int t = 1; t < L_; ++t) {
        float ecur = enext;
        if (t + 1 < L_) enext = eb[(size_t)(t + 1) * K_ + lane];
        float M = dstate;
        #pragma unroll
        for (int off = 32; off; off >>= 1) M = fmaxf(M, __shfl_xor(M, off));
        float e = __expf(dstate - M);
        __syncthreads();
        els[lane] = e;
        __syncthreads();
        float s = 0.f;
        #pragma unroll
        for (int i = 0; i < 64; i += 4) {
            float4 ev = *reinterpret_cast<const float4*>(&els[i]);
            s = fmaf(ev.x, expT[i], s);
            s = fmaf(ev.y, expT[i + 1], s);
            s = fmaf(ev.z, expT[i + 2], s);
            s = fmaf(ev.w, expT[i + 3], s);
        }
        dstate = M + __logf(s) + ecur;
    }
    float M = dstate;
    #pragma unroll
    for (int off = 32; off; off >>= 1) M = fmaxf(M, __shfl_xor(M, off));
    float e = __expf(dstate - M);
    float s = e;
    #pragma unroll
    for (int off = 32; off; off >>= 1) s += __shfl_xor(s, off);
    float logZ = M + __logf(s);
    if (lane == 0) out[b] = -(gold - logZ);
}

// ---------------------------------------------------------------------------
// Workspace layout (bytes). Overlays (disjoint lifetimes):
//   xb aliases hcat; emit aliases pre3 head.
// ---------------------------------------------------------------------------
#define OFF_PRE    ((size_t)0)                        // 268435456
#define OFF_EMIT   OFF_PRE                            // 16777216 (alias)
#define OFF_HCAT   ((size_t)268435456)                // 67108864
#define OFF_XB     OFF_HCAT                           // 67108864 (alias)
#define OFF_WHH8   ((size_t)(OFF_HCAT + 67108864))    // 524288
#define OFF_WEMIT  ((size_t)(OFF_WHH8 + 524288))      // 65536
#define OFF_WP     ((size_t)(OFF_WEMIT + 65536))      // 2097152
#define OFF_BIAS   ((size_t)(OFF_WP + 2097152))       // 8192

extern "C" void kernel_launch(void* const* d_in, const int* in_sizes, int n_in,
                              void* d_out, int out_size, void* d_ws, size_t ws_size,
                              hipStream_t stream) {
    const float* x      = (const float*)d_in[0];
    const int*   labels = (const int*)d_in[1];
    const float* wihf   = (const float*)d_in[2];
    const float* whhf   = (const float*)d_in[3];
    const float* bihf   = (const float*)d_in[4];
    const float* bhhf   = (const float*)d_in[5];
    const float* wihb   = (const float*)d_in[6];
    const float* whhb   = (const float*)d_in[7];
    const float* bihb   = (const float*)d_in[8];
    const float* bhhb   = (const float*)d_in[9];
    const float* wemit  = (const float*)d_in[10];
    const float* bemit  = (const float*)d_in[11];
    const float* trans  = (const float*)d_in[12];
    float* out = (float*)d_out;

    char* ws = (char*)d_ws;
    unsigned short* pre3   = (unsigned short*)(ws + OFF_PRE);
    unsigned short* hcat   = (unsigned short*)(ws + OFF_HCAT);
    unsigned short* xb     = (unsigned short*)(ws + OFF_XB);
    float*          emit   = (float*)(ws + OFF_EMIT);
    unsigned char*  whh8   = (unsigned char*)(ws + OFF_WHH8);
    unsigned short* we_bf  = (unsigned short*)(ws + OFF_WEMIT);
    unsigned short* wp     = (unsigned short*)(ws + OFF_WP);
    float*          bias_p = (float*)(ws + OFF_BIAS);

    setup_convert<<<1024, 256, 0, stream>>>(whhf, whhb, wemit, wihf, wihb,
                                            bihf, bhhf, bihb, bhhb,
                                            whh8, we_bf, wp, bias_p);
    convert_x<<<16384, 256, 0, stream>>>(x, xb);
    pre_gemm<<<dim3(16, 512), 256, 0, stream>>>(xb, wp, bias_p, pre3);
    lstm_scan<<<32, 512, 0, stream>>>(pre3, whh8, hcat);
    emit_gemm<<<1024, 256, 0, stream>>>(hcat, we_bf, bemit, emit);
    crf_kernel<<<128, 64, 0, stream>>>(emit, labels, trans, out);
}

// Round 5
// 1248.371 us; speedup vs baseline: 1.9311x; 1.3060x over previous
//
#include <hip/hip_runtime.h>
#include <hip/hip_bf16.h>

#define B_   128
#define L_   512
#define E_   512
#define H_   256
#define K_   64
#define G4H  1024   // 4*H
#define LOG2E 1.4426950408889634f

typedef __bf16 bf16x8 __attribute__((ext_vector_type(8)));
typedef float  f32x4  __attribute__((ext_vector_type(4)));
typedef int    i32x8  __attribute__((ext_vector_type(8)));

__device__ inline unsigned short f2bf(float f) {
    unsigned int x = __builtin_bit_cast(unsigned int, f);
    unsigned int r = (x + 0x7fffu + ((x >> 16) & 1u)) >> 16;
    return (unsigned short)r;
}
__device__ inline float bf2f(unsigned short u) {
    unsigned int x = ((unsigned int)u) << 16;
    return __builtin_bit_cast(float, x);
}
__device__ inline unsigned int pack2(float lo, float hi) {
    return (unsigned int)f2bf(lo) | ((unsigned int)f2bf(hi) << 16);
}
__device__ inline float ex2(float x) { return __builtin_amdgcn_exp2f(x); }
__device__ inline float rcp_(float x) { return __builtin_amdgcn_rcpf(x); }

// async global->LDS, 16B per lane; LDS dest must be wave-uniform + lane*16
__device__ inline void gl_lds16(const unsigned short* g, unsigned short* l) {
    __builtin_amdgcn_global_load_lds(
        (const __attribute__((address_space(1))) unsigned int*)g,
        (__attribute__((address_space(3))) unsigned int*)l, 16, 0, 0);
}

// ---------------------------------------------------------------------------
// Setup: whh -> fp8 e4m3 scaled by LOG2E; w_emit -> bf16;
// w_ih -> bf16 * LOG2E with gate-interleaved row perm wp[n'=col*4+gate];
// bias_p = (b_ih + b_hh) * LOG2E, permuted.
// ---------------------------------------------------------------------------
__global__ void setup_convert(const float* __restrict__ whh_f, const float* __restrict__ whh_b,
                              const float* __restrict__ wemit,
                              const float* __restrict__ wihf, const float* __restrict__ wihb,
                              const float* __restrict__ bihf, const float* __restrict__ bhhf,
                              const float* __restrict__ bihb, const float* __restrict__ bhhb,
                              unsigned char* __restrict__ whh8,
                              unsigned short* __restrict__ wemit_bf,
                              unsigned short* __restrict__ wp,
                              float* __restrict__ bias_p) {
    int i = blockIdx.x * 256 + threadIdx.x;       // grid 1024*256 = 262144
    if (i < 262144) {
        int j = 2 * i;
        float v0 = (j < 262144) ? whh_f[j] : whh_b[j - 262144];
        float v1 = (j + 1 < 262144) ? whh_f[j + 1] : whh_b[j + 1 - 262144];
        int pk = __builtin_amdgcn_cvt_pk_fp8_f32(v0 * LOG2E, v1 * LOG2E, 0, false);
        ((unsigned short*)whh8)[i] = (unsigned short)(pk & 0xffff);
    }
    if (i < K_ * 2 * H_) wemit_bf[i] = f2bf(wemit[i]);
    if (i < 131072) {
        int rp = i >> 6;            // permuted row 0..2047
        int k8 = (i & 63) * 8;
        int dd = rp >> 10, np = rp & 1023;
        int srow = (np & 3) * 256 + (np >> 2);
        const float* src = (dd == 0 ? wihf : wihb) + (size_t)srow * 512 + k8;
        float4 a  = *reinterpret_cast<const float4*>(src);
        float4 b2 = *reinterpret_cast<const float4*>(src + 4);
        uint4 pk = { pack2(a.x * LOG2E, a.y * LOG2E), pack2(a.z * LOG2E, a.w * LOG2E),
                     pack2(b2.x * LOG2E, b2.y * LOG2E), pack2(b2.z * LOG2E, b2.w * LOG2E) };
        *reinterpret_cast<uint4*>(wp + (size_t)rp * 512 + k8) = pk;
    }
    if (i < 2048) {
        int dd = i >> 10, np = i & 1023;
        int srow = (np & 3) * 256 + (np >> 2);
        bias_p[i] = ((dd == 0) ? (bihf[srow] + bhhf[srow]) : (bihb[srow] + bhhb[srow])) * LOG2E;
    }
}

// x (B,L,E) fp32 -> bf16, same layout
__global__ void convert_x(const float* __restrict__ x, unsigned short* __restrict__ xb) {
    int i = blockIdx.x * 256 + threadIdx.x;     // 16384 blocks
    float4 a = reinterpret_cast<const float4*>(x)[i * 2];
    float4 b = reinterpret_cast<const float4*>(x)[i * 2 + 1];
    uint4 p = { pack2(a.x, a.y), pack2(a.z, a.w), pack2(b.x, b.y), pack2(b.z, b.w) };
    reinterpret_cast<uint4*>(xb)[i] = p;
}

// ---------------------------------------------------------------------------
// pre3[d][b][l][n'] (bf16, b-major), n' = col*4+gate, scaled by LOG2E.
// m97-style: 128x128 tile, BK=32, global_load_lds(16B). M-tile = one b, 128 l.
// ---------------------------------------------------------------------------
__global__ __launch_bounds__(256) void pre_gemm(
    const unsigned short* __restrict__ xb,    // (B,L,E) bf16
    const unsigned short* __restrict__ wp,    // (2048,512) bf16 permuted*LOG2E
    const float* __restrict__ bias_p,         // (2048) permuted*LOG2E
    unsigned short* __restrict__ pre3)        // [2][128][512][1024]
{
    __shared__ unsigned short A_lds[128 * 32];   // [row][k], 64B/row (no pad: DMA linear)
    __shared__ unsigned short B_lds[128 * 32];

    int nt = blockIdx.x, mt = blockIdx.y;
    int tid = threadIdx.x;
    int n0 = nt * 128;
    int b  = mt >> 2, l0 = (mt & 3) * 128;
    int w = tid >> 6, lane = tid & 63;
    int q = lane >> 4, ln = lane & 15;
    int wm = (w >> 1) * 64, wn = (w & 1) * 64;

    f32x4 acc[4][4];
    #pragma unroll
    for (int i = 0; i < 4; ++i)
        #pragma unroll
        for (int j = 0; j < 4; ++j) acc[i][j] = (f32x4){0.f, 0.f, 0.f, 0.f};

    int r_ = tid >> 2, kp = (tid & 3) * 8;
    const unsigned short* asrc0 = xb + ((size_t)b * 512 + l0 + r_) * 512 + kp;
    const unsigned short* asrc1 = asrc0 + (size_t)64 * 512;
    const unsigned short* bsrc0 = wp + (size_t)(n0 + r_) * 512 + kp;
    const unsigned short* bsrc1 = bsrc0 + (size_t)64 * 512;
    unsigned short* adst0 = &A_lds[tid * 8];
    unsigned short* adst1 = &A_lds[2048 + tid * 8];
    unsigned short* bdst0 = &B_lds[tid * 8];
    unsigned short* bdst1 = &B_lds[2048 + tid * 8];

    for (int kc = 0; kc < 16; ++kc) {
        int k0 = kc * 32;
        gl_lds16(asrc0 + k0, adst0);
        gl_lds16(asrc1 + k0, adst1);
        gl_lds16(bsrc0 + k0, bdst0);
        gl_lds16(bsrc1 + k0, bdst1);
        __syncthreads();   // drains vmcnt -> LDS filled

        bf16x8 af[4], bfv[4];
        #pragma unroll
        for (int ms = 0; ms < 4; ++ms)
            af[ms] = *reinterpret_cast<const bf16x8*>(&A_lds[(wm + ms * 16 + ln) * 32 + q * 8]);
        #pragma unroll
        for (int ns = 0; ns < 4; ++ns)
            bfv[ns] = *reinterpret_cast<const bf16x8*>(&B_lds[(wn + ns * 16 + ln) * 32 + q * 8]);
        #pragma unroll
        for (int ms = 0; ms < 4; ++ms)
            #pragma unroll
            for (int ns = 0; ns < 4; ++ns)
                acc[ms][ns] = __builtin_amdgcn_mfma_f32_16x16x32_bf16(af[ms], bfv[ns], acc[ms][ns], 0, 0, 0);
        __syncthreads();   // frag reads done before next DMA overwrites
    }

    #pragma unroll
    for (int ns = 0; ns < 4; ++ns) {
        int n = n0 + wn + ns * 16 + ln;
        float bias = bias_p[n];
        int dsel = n >> 10, np = n & 1023;
        #pragma unroll
        for (int ms = 0; ms < 4; ++ms) {
            #pragma unroll
            for (int rg = 0; rg < 4; ++rg) {
                int l = l0 + wm + ms * 16 + q * 4 + rg;
                pre3[(((size_t)dsel * 128 + b) * 512 + l) * 1024 + np] = f2bf(acc[ms][ns][rg] + bias);
            }
        }
    }
}

// ---------------------------------------------------------------------------
// LSTM scan: 256 WGs, ONE sequence (d,b) per WG -> all 256 CUs on the scan.
// 512 threads = 8 waves. MX fp8 MFMA 16x16x128 (M=16 tile, 1 valid row),
// W_hh register-resident (64 VGPR/thread). Wave w owns tiles T = g*16+(w+8s).
// Valid G row lives in lanes q==0, acc[g][s][0] -> scatter 8 b32 to g_lds ->
// barrier -> 256 threads activate 1 unit each (9 transcendentals) ->
// h fp8 to h_lds row 0 + coalesced bf16 hcat -> barrier.
// pre3 is b-major: each WG streams a contiguous 1 MB region, 2-deep prefetch.
// ---------------------------------------------------------------------------
__global__ __launch_bounds__(512, 2) void lstm_scan(
    const unsigned short* __restrict__ pre3,  // [2][128][512][1024] bf16 (scaled)
    const unsigned char* __restrict__ whh8,   // [2][1024][256] fp8 e4m3 (scaled)
    unsigned short* __restrict__ hcat)        // [512][128][512] bf16
{
    __shared__ unsigned char h_lds[2][16 * 272];   // fp8; rows 1..15 stay 0
    __shared__ float g_lds[1024 + 32];             // [n' = col*4+gate]

    int wg = blockIdx.x;           // 256 = 2 dirs x 128 batch
    int d = wg >> 7, b = wg & 127;
    int tid = threadIdx.x, w = tid >> 6, lane = tid & 63;
    int q = lane >> 4, ln = lane & 15;

    const unsigned char* whh_d = whh8 + (size_t)d * (1024 * 256);
    const unsigned short* pre_wg = pre3 + ((size_t)d * 128 + b) * (512 * 1024);

    // W_hh B-frags: tile T = g*16 + (w+8s); B[n=T*16+ln][k=kc*128+q*32+j]
    i32x8 wh[4][2][2];
    #pragma unroll
    for (int g = 0; g < 4; ++g)
        #pragma unroll
        for (int s = 0; s < 2; ++s) {
            int row = g * 256 + (w + 8 * s) * 16 + ln;
            #pragma unroll
            for (int kc = 0; kc < 2; ++kc)
                wh[g][s][kc] = *reinterpret_cast<const i32x8*>(
                    whh_d + (size_t)row * 256 + kc * 128 + q * 32);
        }

    for (int i = tid; i < (2 * 16 * 272) / 4; i += 512) ((int*)h_lds)[i] = 0;

    // activation: thread tid<256 owns hidden col = tid
    int col = tid;
    bool act = (tid < 256);

    ushort4 p0 = {0,0,0,0}, p1 = {0,0,0,0};
    if (act) {
        int la = (d == 0) ? 0 : (L_ - 1);
        int lb_ = (d == 0) ? 1 : (L_ - 2);
        p0 = *reinterpret_cast<const ushort4*>(pre_wg + (size_t)la * 1024 + col * 4);
        p1 = *reinterpret_cast<const ushort4*>(pre_wg + (size_t)lb_ * 1024 + col * 4);
    }
    __syncthreads();

    float cst = 0.f;

    for (int t = 0; t < L_; ++t) {
        int p = t & 1;
        int l = (d == 0) ? t : (L_ - 1 - t);

        // prefetch pre[t+2] (2-deep: covers ~2 steps of HBM latency)
        ushort4 p2 = {0,0,0,0};
        if (act) {
            int t2 = (t + 2 < L_) ? (t + 2) : (L_ - 1);
            int l2 = (d == 0) ? t2 : (L_ - 1 - t2);
            p2 = *reinterpret_cast<const ushort4*>(pre_wg + (size_t)l2 * 1024 + col * 4);
        }

        // ---- MFMA: G = h @ W_hh^T (MX fp8, K=256 = 2 chunks of 128) ----
        f32x4 acc[4][2];
        #pragma unroll
        for (int g = 0; g < 4; ++g) {
            acc[g][0] = (f32x4){0.f, 0.f, 0.f, 0.f};
            acc[g][1] = (f32x4){0.f, 0.f, 0.f, 0.f};
        }
        #pragma unroll
        for (int kc = 0; kc < 2; ++kc) {
            const unsigned char* ab = &h_lds[p][ln * 272 + kc * 128 + q * 32];
            uint4 a0 = *reinterpret_cast<const uint4*>(ab);
            uint4 a1 = *reinterpret_cast<const uint4*>(ab + 16);
            i32x8 af = { (int)a0.x, (int)a0.y, (int)a0.z, (int)a0.w,
                         (int)a1.x, (int)a1.y, (int)a1.z, (int)a1.w };
            #pragma unroll
            for (int g = 0; g < 4; ++g)
                #pragma unroll
                for (int s = 0; s < 2; ++s)
                    acc[g][s] = __builtin_amdgcn_mfma_scale_f32_16x16x128_f8f6f4(
                        af, wh[g][s][kc], acc[g][s], 0, 0,
                        0, 0x7f7f7f7f, 0, 0x7f7f7f7f);
        }

        // ---- scatter valid row (q==0, reg 0) to g_lds ----
        if (q == 0) {
            #pragma unroll
            for (int g = 0; g < 4; ++g)
                #pragma unroll
                for (int s = 0; s < 2; ++s)
                    g_lds[((w + 8 * s) * 16 + ln) * 4 + g] = acc[g][s][0];
        }
        __syncthreads();

        // ---- activation: 1 unit per thread (tid<256), 9 transcendentals ----
        if (act) {
            f32x4 gv = *reinterpret_cast<const f32x4*>(&g_lds[col * 4]);
            float vi = gv.x + bf2f(p0.x);
            float vf = gv.y + bf2f(p0.y);
            float vg = gv.z + bf2f(p0.z);
            float vo = gv.w + bf2f(p0.w);
            float ei  = ex2(vi);
            float e2g = ex2(vg + vg);
            float itg = (ei * (e2g - 1.f)) * rcp_((1.f + ei) * (1.f + e2g));  // sigm(i)*tanh(g)
            float sf  = rcp_(1.f + ex2(-vf));
            float cn  = fmaf(sf, cst, itg);
            cst = cn;
            float tc  = fmaf(-2.f, rcp_(1.f + ex2((2.f * LOG2E) * cn)), 1.f); // tanh(c), inf-safe
            float so  = rcp_(1.f + ex2(-vo));
            float hn  = so * tc;
            int pk = __builtin_amdgcn_cvt_pk_fp8_f32(hn, hn, 0, false);
            h_lds[p ^ 1][col] = (unsigned char)(pk & 0xff);
            hcat[((size_t)l * 128 + b) * 512 + d * 256 + col] = f2bf(hn);
        }
        __syncthreads();   // h_lds[p^1] row 0 ready; g_lds reads done

        p0 = p1; p1 = p2;
    }
}

// ---------------------------------------------------------------------------
// emit[b][l][k] = hcat[l][b][:] . w_emit[k][:] + b_emit[k]   (fp32 out)
// ---------------------------------------------------------------------------
__global__ __launch_bounds__(256) void emit_gemm(
    const unsigned short* __restrict__ hcat,   // [L*B][512]
    const unsigned short* __restrict__ wemit,  // [64][512]
    const float* __restrict__ bemit,           // [64]
    float* __restrict__ emit)                  // [B][L][64]
{
    int m0 = blockIdx.x * 64;
    int tid = threadIdx.x, w = tid >> 6, lane = tid & 63;
    int quad = lane >> 4, ln = lane & 15;
    int mrow = m0 + w * 16;

    f32x4 acc[4];
    #pragma unroll
    for (int i = 0; i < 4; ++i) acc[i] = (f32x4){0.f, 0.f, 0.f, 0.f};

    const unsigned short* arow = hcat + (size_t)(mrow + ln) * 512;
    #pragma unroll 4
    for (int kc = 0; kc < 16; ++kc) {
        bf16x8 af = *reinterpret_cast<const bf16x8*>(arow + kc * 32 + quad * 8);
        #pragma unroll
        for (int T = 0; T < 4; ++T) {
            bf16x8 bfv = *reinterpret_cast<const bf16x8*>(wemit + (size_t)(T * 16 + ln) * 512 + kc * 32 + quad * 8);
            acc[T] = __builtin_amdgcn_mfma_f32_16x16x32_bf16(af, bfv, acc[T], 0, 0, 0);
        }
    }
    #pragma unroll
    for (int T = 0; T < 4; ++T) {
        int k = T * 16 + ln;
        float bias = bemit[k];
        #pragma unroll
        for (int rg = 0; rg < 4; ++rg) {
            int m = mrow + quad * 4 + rg;
            int ll = m >> 7, bidx = m & 127;
            emit[((size_t)bidx * L_ + ll) * K_ + k] = acc[T][rg] + bias;
        }
    }
}

// ---------------------------------------------------------------------------
// CRF: per batch row, 511 sequential steps.
// lse_i(d_i + T[i,k]) = M + log( sum_i exp(d_i - M) * expT[i][k] )
// ---------------------------------------------------------------------------
__global__ __launch_bounds__(64) void crf_kernel(
    const float* __restrict__ emit,    // [B][L][64]
    const int* __restrict__ labels,    // [B][L]
    const float* __restrict__ trans,   // [64][64]
    float* __restrict__ out)           // [B]
{
    __shared__ float els[64];
    int b = blockIdx.x, lane = threadIdx.x;
    const float* eb = emit + (size_t)b * L_ * K_;
    const int* lb = labels + (size_t)b * L_;

    float gold = 0.f;
    for (int t = lane; t < L_; t += 64) gold += eb[(size_t)t * K_ + lb[t]];
    for (int t = lane; t < L_ - 1; t += 64) gold += trans[lb[t] * K_ + lb[t + 1]];
    #pragma unroll
    for (int off = 32; off; off >>= 1) gold += __shfl_down(gold, off);

    float expT[64];   // column `lane` of exp(T)
    #pragma unroll
    for (int i = 0; i < 64; ++i) expT[i] = __expf(trans[i * K_ + lane]);

    float dstate = eb[lane];
    float enext = eb[K_ + lane];
    for (int t = 1; t < L_; ++t) {
        float ecur = enext;
        if (t + 1 < L_) enext = eb[(size_t)(t + 1) * K_ + lane];
        float M = dstate;
        #pragma unroll
        for (int off = 32; off; off >>= 1) M = fmaxf(M, __shfl_xor(M, off));
        float e = __expf(dstate - M);
        __syncthreads();
        els[lane] = e;
        __syncthreads();
        float s = 0.f;
        #pragma unroll
        for (int i = 0; i < 64; i += 4) {
            float4 ev = *reinterpret_cast<const float4*>(&els[i]);
            s = fmaf(ev.x, expT[i], s);
            s = fmaf(ev.y, expT[i + 1], s);
            s = fmaf(ev.z, expT[i + 2], s);
            s = fmaf(ev.w, expT[i + 3], s);
        }
        dstate = M + __logf(s) + ecur;
    }
    float M = dstate;
    #pragma unroll
    for (int off = 32; off; off >>= 1) M = fmaxf(M, __shfl_xor(M, off));
    float e = __expf(dstate - M);
    float s = e;
    #pragma unroll
    for (int off = 32; off; off >>= 1) s += __shfl_xor(s, off);
    float logZ = M + __logf(s);
    if (lane == 0) out[b] = -(gold - logZ);
}

// ---------------------------------------------------------------------------
// Workspace layout (bytes). Overlays (disjoint lifetimes):
//   xb aliases hcat; emit aliases pre3 head.
// ---------------------------------------------------------------------------
#define OFF_PRE    ((size_t)0)                        // 268435456
#define OFF_EMIT   OFF_PRE                            // 16777216 (alias)
#define OFF_HCAT   ((size_t)268435456)                // 67108864
#define OFF_XB     OFF_HCAT                           // 67108864 (alias)
#define OFF_WHH8   ((size_t)(OFF_HCAT + 67108864))    // 524288
#define OFF_WEMIT  ((size_t)(OFF_WHH8 + 524288))      // 65536
#define OFF_WP     ((size_t)(OFF_WEMIT + 65536))      // 2097152
#define OFF_BIAS   ((size_t)(OFF_WP + 2097152))       // 8192

extern "C" void kernel_launch(void* const* d_in, const int* in_sizes, int n_in,
                              void* d_out, int out_size, void* d_ws, size_t ws_size,
                              hipStream_t stream) {
    const float* x      = (const float*)d_in[0];
    const int*   labels = (const int*)d_in[1];
    const float* wihf   = (const float*)d_in[2];
    const float* whhf   = (const float*)d_in[3];
    const float* bihf   = (const float*)d_in[4];
    const float* bhhf   = (const float*)d_in[5];
    const float* wihb   = (const float*)d_in[6];
    const float* whhb   = (const float*)d_in[7];
    const float* bihb   = (const float*)d_in[8];
    const float* bhhb   = (const float*)d_in[9];
    const float* wemit  = (const float*)d_in[10];
    const float* bemit  = (const float*)d_in[11];
    const float* trans  = (const float*)d_in[12];
    float* out = (float*)d_out;

    char* ws = (char*)d_ws;
    unsigned short* pre3   = (unsigned short*)(ws + OFF_PRE);
    unsigned short* hcat   = (unsigned short*)(ws + OFF_HCAT);
    unsigned short* xb     = (unsigned short*)(ws + OFF_XB);
    float*          emit   = (float*)(ws + OFF_EMIT);
    unsigned char*  whh8   = (unsigned char*)(ws + OFF_WHH8);
    unsigned short* we_bf  = (unsigned short*)(ws + OFF_WEMIT);
    unsigned short* wp     = (unsigned short*)(ws + OFF_WP);
    float*          bias_p = (float*)(ws + OFF_BIAS);

    setup_convert<<<1024, 256, 0, stream>>>(whhf, whhb, wemit, wihf, wihb,
                                            bihf, bhhf, bihb, bhhb,
                                            whh8, we_bf, wp, bias_p);
    convert_x<<<16384, 256, 0, stream>>>(x, xb);
    pre_gemm<<<dim3(16, 512), 256, 0, stream>>>(xb, wp, bias_p, pre3);
    lstm_scan<<<256, 512, 0, stream>>>(pre3, whh8, hcat);
    emit_gemm<<<1024, 256, 0, stream>>>(hcat, we_bf, bemit, emit);
    crf_kernel<<<128, 64, 0, stream>>>(emit, labels, trans, out);
}

// Round 6
// 1090.044 us; speedup vs baseline: 2.2116x; 1.1452x over previous
//
#include <hip/hip_runtime.h>
#include <hip/hip_bf16.h>

#define B_   128
#define L_   512
#define E_   512
#define H_   256
#define K_   64
#define G4H  1024   // 4*H
#define LOG2E 1.4426950408889634f

typedef __bf16 bf16x8 __attribute__((ext_vector_type(8)));
typedef float  f32x4  __attribute__((ext_vector_type(4)));
typedef int    i32x8  __attribute__((ext_vector_type(8)));

__device__ inline unsigned short f2bf(float f) {
    unsigned int x = __builtin_bit_cast(unsigned int, f);
    unsigned int r = (x + 0x7fffu + ((x >> 16) & 1u)) >> 16;
    return (unsigned short)r;
}
__device__ inline float bf2f(unsigned short u) {
    unsigned int x = ((unsigned int)u) << 16;
    return __builtin_bit_cast(float, x);
}
__device__ inline unsigned int pack2(float lo, float hi) {
    return (unsigned int)f2bf(lo) | ((unsigned int)f2bf(hi) << 16);
}
__device__ inline float ex2(float x) { return __builtin_amdgcn_exp2f(x); }
__device__ inline float rcp_(float x) { return __builtin_amdgcn_rcpf(x); }

// async global->LDS, 16B per lane; LDS dest must be wave-uniform + lane*16
__device__ inline void gl_lds16(const unsigned short* g, unsigned short* l) {
    __builtin_amdgcn_global_load_lds(
        (const __attribute__((address_space(1))) unsigned int*)g,
        (__attribute__((address_space(3))) unsigned int*)l, 16, 0, 0);
}

// ---------------------------------------------------------------------------
// Setup: whh -> fp8 e4m3 scaled by LOG2E; w_emit -> bf16;
// w_ih -> bf16 * LOG2E with gate-interleaved row perm wp[n'=col*4+gate];
// bias_p = (b_ih + b_hh) * LOG2E, permuted.
// ---------------------------------------------------------------------------
__global__ void setup_convert(const float* __restrict__ whh_f, const float* __restrict__ whh_b,
                              const float* __restrict__ wemit,
                              const float* __restrict__ wihf, const float* __restrict__ wihb,
                              const float* __restrict__ bihf, const float* __restrict__ bhhf,
                              const float* __restrict__ bihb, const float* __restrict__ bhhb,
                              unsigned char* __restrict__ whh8,
                              unsigned short* __restrict__ wemit_bf,
                              unsigned short* __restrict__ wp,
                              float* __restrict__ bias_p) {
    int i = blockIdx.x * 256 + threadIdx.x;       // grid 1024*256 = 262144
    if (i < 262144) {
        int j = 2 * i;
        float v0 = (j < 262144) ? whh_f[j] : whh_b[j - 262144];
        float v1 = (j + 1 < 262144) ? whh_f[j + 1] : whh_b[j + 1 - 262144];
        int pk = __builtin_amdgcn_cvt_pk_fp8_f32(v0 * LOG2E, v1 * LOG2E, 0, false);
        ((unsigned short*)whh8)[i] = (unsigned short)(pk & 0xffff);
    }
    if (i < K_ * 2 * H_) wemit_bf[i] = f2bf(wemit[i]);
    if (i < 131072) {
        int rp = i >> 6;            // permuted row 0..2047
        int k8 = (i & 63) * 8;
        int dd = rp >> 10, np = rp & 1023;
        int srow = (np & 3) * 256 + (np >> 2);
        const float* src = (dd == 0 ? wihf : wihb) + (size_t)srow * 512 + k8;
        float4 a  = *reinterpret_cast<const float4*>(src);
        float4 b2 = *reinterpret_cast<const float4*>(src + 4);
        uint4 pk = { pack2(a.x * LOG2E, a.y * LOG2E), pack2(a.z * LOG2E, a.w * LOG2E),
                     pack2(b2.x * LOG2E, b2.y * LOG2E), pack2(b2.z * LOG2E, b2.w * LOG2E) };
        *reinterpret_cast<uint4*>(wp + (size_t)rp * 512 + k8) = pk;
    }
    if (i < 2048) {
        int dd = i >> 10, np = i & 1023;
        int srow = (np & 3) * 256 + (np >> 2);
        bias_p[i] = ((dd == 0) ? (bihf[srow] + bhhf[srow]) : (bihb[srow] + bhhb[srow])) * LOG2E;
    }
}

// x (B,L,E) fp32 -> bf16, same layout
__global__ void convert_x(const float* __restrict__ x, unsigned short* __restrict__ xb) {
    int i = blockIdx.x * 256 + threadIdx.x;     // 16384 blocks
    float4 a = reinterpret_cast<const float4*>(x)[i * 2];
    float4 b = reinterpret_cast<const float4*>(x)[i * 2 + 1];
    uint4 p = { pack2(a.x, a.y), pack2(a.z, a.w), pack2(b.x, b.y), pack2(b.z, b.w) };
    reinterpret_cast<uint4*>(xb)[i] = p;
}

// ---------------------------------------------------------------------------
// pre3[d][b][l][n'] (bf16, b-major), n' = col*4+gate, scaled by LOG2E.
// m97-style: 128x128 tile, BK=32, global_load_lds(16B). M-tile = one b, 128 l.
// ---------------------------------------------------------------------------
__global__ __launch_bounds__(256) void pre_gemm(
    const unsigned short* __restrict__ xb,    // (B,L,E) bf16
    const unsigned short* __restrict__ wp,    // (2048,512) bf16 permuted*LOG2E
    const float* __restrict__ bias_p,         // (2048) permuted*LOG2E
    unsigned short* __restrict__ pre3)        // [2][128][512][1024]
{
    __shared__ unsigned short A_lds[128 * 32];   // [row][k], 64B/row (no pad: DMA linear)
    __shared__ unsigned short B_lds[128 * 32];

    int nt = blockIdx.x, mt = blockIdx.y;
    int tid = threadIdx.x;
    int n0 = nt * 128;
    int b  = mt >> 2, l0 = (mt & 3) * 128;
    int w = tid >> 6, lane = tid & 63;
    int q = lane >> 4, ln = lane & 15;
    int wm = (w >> 1) * 64, wn = (w & 1) * 64;

    f32x4 acc[4][4];
    #pragma unroll
    for (int i = 0; i < 4; ++i)
        #pragma unroll
        for (int j = 0; j < 4; ++j) acc[i][j] = (f32x4){0.f, 0.f, 0.f, 0.f};

    int r_ = tid >> 2, kp = (tid & 3) * 8;
    const unsigned short* asrc0 = xb + ((size_t)b * 512 + l0 + r_) * 512 + kp;
    const unsigned short* asrc1 = asrc0 + (size_t)64 * 512;
    const unsigned short* bsrc0 = wp + (size_t)(n0 + r_) * 512 + kp;
    const unsigned short* bsrc1 = bsrc0 + (size_t)64 * 512;
    unsigned short* adst0 = &A_lds[tid * 8];
    unsigned short* adst1 = &A_lds[2048 + tid * 8];
    unsigned short* bdst0 = &B_lds[tid * 8];
    unsigned short* bdst1 = &B_lds[2048 + tid * 8];

    for (int kc = 0; kc < 16; ++kc) {
        int k0 = kc * 32;
        gl_lds16(asrc0 + k0, adst0);
        gl_lds16(asrc1 + k0, adst1);
        gl_lds16(bsrc0 + k0, bdst0);
        gl_lds16(bsrc1 + k0, bdst1);
        __syncthreads();   // drains vmcnt -> LDS filled

        bf16x8 af[4], bfv[4];
        #pragma unroll
        for (int ms = 0; ms < 4; ++ms)
            af[ms] = *reinterpret_cast<const bf16x8*>(&A_lds[(wm + ms * 16 + ln) * 32 + q * 8]);
        #pragma unroll
        for (int ns = 0; ns < 4; ++ns)
            bfv[ns] = *reinterpret_cast<const bf16x8*>(&B_lds[(wn + ns * 16 + ln) * 32 + q * 8]);
        #pragma unroll
        for (int ms = 0; ms < 4; ++ms)
            #pragma unroll
            for (int ns = 0; ns < 4; ++ns)
                acc[ms][ns] = __builtin_amdgcn_mfma_f32_16x16x32_bf16(af[ms], bfv[ns], acc[ms][ns], 0, 0, 0);
        __syncthreads();   // frag reads done before next DMA overwrites
    }

    #pragma unroll
    for (int ns = 0; ns < 4; ++ns) {
        int n = n0 + wn + ns * 16 + ln;
        float bias = bias_p[n];
        int dsel = n >> 10, np = n & 1023;
        #pragma unroll
        for (int ms = 0; ms < 4; ++ms) {
            #pragma unroll
            for (int rg = 0; rg < 4; ++rg) {
                int l = l0 + wm + ms * 16 + q * 4 + rg;
                pre3[(((size_t)dsel * 128 + b) * 512 + l) * 1024 + np] = f2bf(acc[ms][ns][rg] + bias);
            }
        }
    }
}

// ---------------------------------------------------------------------------
// LSTM scan: 256 WGs, ONE sequence (d,b) per WG. 512 threads = 8 waves.
// MX fp8 MFMA 16x16x128 (M=16 tile, valid row 0), W_hh register-resident.
// NEW (r6): no g_lds, no first barrier. Valid G row sits in acc[g][s][0] of
// lanes 0-15 (q=0). 8 __shfl + 4 selects put all 4 gates of col
// (w+8*(lane>>4))*16+(lane&15) into lanes 0-31 of the SAME wave -> in-register
// activation -> fp8 h byte to h_lds row 0 + bf16 hcat. ONE barrier per step.
// ---------------------------------------------------------------------------
__global__ __launch_bounds__(512, 2) void lstm_scan(
    const unsigned short* __restrict__ pre3,  // [2][128][512][1024] bf16 (scaled)
    const unsigned char* __restrict__ whh8,   // [2][1024][256] fp8 e4m3 (scaled)
    unsigned short* __restrict__ hcat)        // [512][128][512] bf16
{
    __shared__ unsigned char h_lds[2][16 * 272];   // fp8; rows 1..15 stay 0 forever

    int wg = blockIdx.x;           // 256 = 2 dirs x 128 batch
    int d = wg >> 7, b = wg & 127;
    int tid = threadIdx.x, w = tid >> 6, lane = tid & 63;
    int q = lane >> 4, ln = lane & 15;

    const unsigned char* whh_d = whh8 + (size_t)d * (1024 * 256);
    const unsigned short* pre_wg = pre3 + ((size_t)d * 128 + b) * (512 * 1024);

    // W_hh B-frags: tile T = g*16 + (w+8s); B[n=T*16+ln][k=kc*128+q*32+j]
    i32x8 wh[4][2][2];
    #pragma unroll
    for (int g = 0; g < 4; ++g)
        #pragma unroll
        for (int s = 0; s < 2; ++s) {
            int row = g * 256 + (w + 8 * s) * 16 + ln;
            #pragma unroll
            for (int kc = 0; kc < 2; ++kc)
                wh[g][s][kc] = *reinterpret_cast<const i32x8*>(
                    whh_d + (size_t)row * 256 + kc * 128 + q * 32);
        }

    for (int i = tid; i < (2 * 16 * 272) / 4; i += 512) ((int*)h_lds)[i] = 0;

    // activation mapping: lanes 0-31 of each wave own col = (w+8*s)*16+ln
    bool act = (lane < 32);
    int s_  = (lane >> 4) & 1;
    int col = (w + 8 * s_) * 16 + ln;

    ushort4 p0 = {0,0,0,0}, p1 = {0,0,0,0};
    if (act) {
        int la  = (d == 0) ? 0 : (L_ - 1);
        int lb_ = (d == 0) ? 1 : (L_ - 2);
        p0 = *reinterpret_cast<const ushort4*>(pre_wg + (size_t)la * 1024 + col * 4);
        p1 = *reinterpret_cast<const ushort4*>(pre_wg + (size_t)lb_ * 1024 + col * 4);
    }
    __syncthreads();

    float cst = 0.f;

    for (int t = 0; t < L_; ++t) {
        int p = t & 1;
        int l = (d == 0) ? t : (L_ - 1 - t);

        // prefetch pre[t+2]
        ushort4 p2 = {0,0,0,0};
        if (act) {
            int t2 = (t + 2 < L_) ? (t + 2) : (L_ - 1);
            int l2 = (d == 0) ? t2 : (L_ - 1 - t2);
            p2 = *reinterpret_cast<const ushort4*>(pre_wg + (size_t)l2 * 1024 + col * 4);
        }

        // ---- MFMA: G = h @ W_hh^T (MX fp8, K=256 = 2 chunks of 128) ----
        f32x4 acc[4][2];
        #pragma unroll
        for (int g = 0; g < 4; ++g) {
            acc[g][0] = (f32x4){0.f, 0.f, 0.f, 0.f};
            acc[g][1] = (f32x4){0.f, 0.f, 0.f, 0.f};
        }
        #pragma unroll
        for (int kc = 0; kc < 2; ++kc) {
            const unsigned char* ab = &h_lds[p][ln * 272 + kc * 128 + q * 32];
            uint4 a0 = *reinterpret_cast<const uint4*>(ab);
            uint4 a1 = *reinterpret_cast<const uint4*>(ab + 16);
            i32x8 af = { (int)a0.x, (int)a0.y, (int)a0.z, (int)a0.w,
                         (int)a1.x, (int)a1.y, (int)a1.z, (int)a1.w };
            #pragma unroll
            for (int g = 0; g < 4; ++g)
                #pragma unroll
                for (int s = 0; s < 2; ++s)
                    acc[g][s] = __builtin_amdgcn_mfma_scale_f32_16x16x128_f8f6f4(
                        af, wh[g][s][kc], acc[g][s], 0, 0,
                        0, 0x7f7f7f7f, 0, 0x7f7f7f7f);
        }

        // ---- in-register redistribution: lane<32 gets its col's 4 gates ----
        float gv[4];
        #pragma unroll
        for (int g = 0; g < 4; ++g) {
            float lo = __shfl(acc[g][0][0], ln);   // from q=0 holder lane ln
            float hi = __shfl(acc[g][1][0], ln);
            gv[g] = s_ ? hi : lo;
        }

        // ---- activation on lanes 0-31 (1 unit each) ----
        if (act) {
            float vi = gv[0] + bf2f(p0.x);
            float vf = gv[1] + bf2f(p0.y);
            float vg = gv[2] + bf2f(p0.z);
            float vo = gv[3] + bf2f(p0.w);
            float ei  = ex2(vi);
            float e2g = ex2(vg + vg);
            float itg = (ei * (e2g - 1.f)) * rcp_((1.f + ei) * (1.f + e2g));  // sigm(i)*tanh(g)
            float sf  = rcp_(1.f + ex2(-vf));
            float cn  = fmaf(sf, cst, itg);
            cst = cn;
            float tc  = fmaf(-2.f, rcp_(1.f + ex2((2.f * LOG2E) * cn)), 1.f); // tanh(c)
            float so  = rcp_(1.f + ex2(-vo));
            float hn  = so * tc;
            int pk = __builtin_amdgcn_cvt_pk_fp8_f32(hn, hn, 0, false);
            h_lds[p ^ 1][col] = (unsigned char)(pk & 0xff);
            hcat[((size_t)l * 128 + b) * 512 + d * 256 + col] = f2bf(hn);
        }
        __syncthreads();   // h_lds[p^1] row 0 ready for all waves

        p0 = p1; p1 = p2;
    }
}

// ---------------------------------------------------------------------------
// emit[b][l][k] = hcat[l][b][:] . w_emit[k][:] + b_emit[k]   (fp32 out)
// ---------------------------------------------------------------------------
__global__ __launch_bounds__(256) void emit_gemm(
    const unsigned short* __restrict__ hcat,   // [L*B][512]
    const unsigned short* __restrict__ wemit,  // [64][512]
    const float* __restrict__ bemit,           // [64]
    float* __restrict__ emit)                  // [B][L][64]
{
    int m0 = blockIdx.x * 64;
    int tid = threadIdx.x, w = tid >> 6, lane = tid & 63;
    int quad = lane >> 4, ln = lane & 15;
    int mrow = m0 + w * 16;

    f32x4 acc[4];
    #pragma unroll
    for (int i = 0; i < 4; ++i) acc[i] = (f32x4){0.f, 0.f, 0.f, 0.f};

    const unsigned short* arow = hcat + (size_t)(mrow + ln) * 512;
    #pragma unroll 4
    for (int kc = 0; kc < 16; ++kc) {
        bf16x8 af = *reinterpret_cast<const bf16x8*>(arow + kc * 32 + quad * 8);
        #pragma unroll
        for (int T = 0; T < 4; ++T) {
            bf16x8 bfv = *reinterpret_cast<const bf16x8*>(wemit + (size_t)(T * 16 + ln) * 512 + kc * 32 + quad * 8);
            acc[T] = __builtin_amdgcn_mfma_f32_16x16x32_bf16(af, bfv, acc[T], 0, 0, 0);
        }
    }
    #pragma unroll
    for (int T = 0; T < 4; ++T) {
        int k = T * 16 + ln;
        float bias = bemit[k];
        #pragma unroll
        for (int rg = 0; rg < 4; ++rg) {
            int m = mrow + quad * 4 + rg;
            int ll = m >> 7, bidx = m & 127;
            emit[((size_t)bidx * L_ + ll) * K_ + k] = acc[T][rg] + bias;
        }
    }
}

// ---------------------------------------------------------------------------
// CRF: per batch row, 511 sequential steps.
// r6: normalization uses readfirstlane(d) instead of a 6-shfl max — the
// d-spread across states is bounded (~±5), so exp stays in fp32 range.
// ---------------------------------------------------------------------------
__global__ __launch_bounds__(64) void crf_kernel(
    const float* __restrict__ emit,    // [B][L][64]
    const int* __restrict__ labels,    // [B][L]
    const float* __restrict__ trans,   // [64][64]
    float* __restrict__ out)           // [B]
{
    __shared__ float els[64];
    int b = blockIdx.x, lane = threadIdx.x;
    const float* eb = emit + (size_t)b * L_ * K_;
    const int* lb = labels + (size_t)b * L_;

    float gold = 0.f;
    for (int t = lane; t < L_; t += 64) gold += eb[(size_t)t * K_ + lb[t]];
    for (int t = lane; t < L_ - 1; t += 64) gold += trans[lb[t] * K_ + lb[t + 1]];
    #pragma unroll
    for (int off = 32; off; off >>= 1) gold += __shfl_down(gold, off);

    float expT[64];   // column `lane` of exp(T)
    #pragma unroll
    for (int i = 0; i < 64; ++i) expT[i] = __expf(trans[i * K_ + lane]);

    float dstate = eb[lane];
    float enext = eb[K_ + lane];
    for (int t = 1; t < L_; ++t) {
        float ecur = enext;
        if (t + 1 < L_) enext = eb[(size_t)(t + 1) * K_ + lane];
        float M = __builtin_amdgcn_readfirstlane(dstate);   // cheap shared shift
        float e = __expf(dstate - M);
        __syncthreads();
        els[lane] = e;
        __syncthreads();
        float s = 0.f;
        #pragma unroll
        for (int i = 0; i < 64; i += 4) {
            float4 ev = *reinterpret_cast<const float4*>(&els[i]);
            s = fmaf(ev.x, expT[i], s);
            s = fmaf(ev.y, expT[i + 1], s);
            s = fmaf(ev.z, expT[i + 2], s);
            s = fmaf(ev.w, expT[i + 3], s);
        }
        dstate = M + __logf(s) + ecur;
    }
    float M = __builtin_amdgcn_readfirstlane(dstate);
    float e = __expf(dstate - M);
    float s = e;
    #pragma unroll
    for (int off = 32; off; off >>= 1) s += __shfl_xor(s, off);
    float logZ = M + __logf(s);
    if (lane == 0) out[b] = -(gold - logZ);
}

// ---------------------------------------------------------------------------
// Workspace layout (bytes). Overlays (disjoint lifetimes):
//   xb aliases hcat; emit aliases pre3 head.
// ---------------------------------------------------------------------------
#define OFF_PRE    ((size_t)0)                        // 268435456
#define OFF_EMIT   OFF_PRE                            // 16777216 (alias)
#define OFF_HCAT   ((size_t)268435456)                // 67108864
#define OFF_XB     OFF_HCAT                           // 67108864 (alias)
#define OFF_WHH8   ((size_t)(OFF_HCAT + 67108864))    // 524288
#define OFF_WEMIT  ((size_t)(OFF_WHH8 + 524288))      // 65536
#define OFF_WP     ((size_t)(OFF_WEMIT + 65536))      // 2097152
#define OFF_BIAS   ((size_t)(OFF_WP + 2097152))       // 8192

extern "C" void kernel_launch(void* const* d_in, const int* in_sizes, int n_in,
                              void* d_out, int out_size, void* d_ws, size_t ws_size,
                              hipStream_t stream) {
    const float* x      = (const float*)d_in[0];
    const int*   labels = (const int*)d_in[1];
    const float* wihf   = (const float*)d_in[2];
    const float* whhf   = (const float*)d_in[3];
    const float* bihf   = (const float*)d_in[4];
    const float* bhhf   = (const float*)d_in[5];
    const float* wihb   = (const float*)d_in[6];
    const float* whhb   = (const float*)d_in[7];
    const float* bihb   = (const float*)d_in[8];
    const float* bhhb   = (const float*)d_in[9];
    const float* wemit  = (const float*)d_in[10];
    const float* bemit  = (const float*)d_in[11];
    const float* trans  = (const float*)d_in[12];
    float* out = (float*)d_out;

    char* ws = (char*)d_ws;
    unsigned short* pre3   = (unsigned short*)(ws + OFF_PRE);
    unsigned short* hcat   = (unsigned short*)(ws + OFF_HCAT);
    unsigned short* xb     = (unsigned short*)(ws + OFF_XB);
    float*          emit   = (float*)(ws + OFF_EMIT);
    unsigned char*  whh8   = (unsigned char*)(ws + OFF_WHH8);
    unsigned short* we_bf  = (unsigned short*)(ws + OFF_WEMIT);
    unsigned short* wp     = (unsigned short*)(ws + OFF_WP);
    float*          bias_p = (float*)(ws + OFF_BIAS);

    setup_convert<<<1024, 256, 0, stream>>>(whhf, whhb, wemit, wihf, wihb,
                                            bihf, bhhf, bihb, bhhb,
                                            whh8, we_bf, wp, bias_p);
    convert_x<<<16384, 256, 0, stream>>>(x, xb);
    pre_gemm<<<dim3(16, 512), 256, 0, stream>>>(xb, wp, bias_p, pre3);
    lstm_scan<<<256, 512, 0, stream>>>(pre3, whh8, hcat);
    emit_gemm<<<1024, 256, 0, stream>>>(hcat, we_bf, bemit, emit);
    crf_kernel<<<128, 64, 0, stream>>>(emit, labels, trans, out);
}